// Round 7
// baseline (1167.942 us; speedup 1.0000x reference)
//
#include <hip/hip_runtime.h>

#define PAD 96

// ---------------- adjacency build ----------------

__global__ void fill_zero_i32(int* __restrict__ p, int n) {
    int i = blockIdx.x * blockDim.x + threadIdx.x;
    if (i < n) p[i] = 0;
}

__global__ void build_adj(const int* __restrict__ ei, int* __restrict__ cnt,
                          int* __restrict__ col, int E) {
    int e = blockIdx.x * blockDim.x + threadIdx.x;
    if (e >= E) return;
    int src = ei[e];
    int dst = ei[E + e];
    int slot = atomicAdd(&cnt[dst], 1);
    if (slot < PAD) col[(size_t)dst * PAD + slot] = src;
}

// ---------------- weight transposes ----------------
// W[64][K] row-major -> Wt[K][64]

template <int K>
__global__ void transpose_pair(const float* __restrict__ Wl,
                               const float* __restrict__ Wr,
                               float* __restrict__ wtA,
                               float* __restrict__ wtB) {
    int t = blockIdx.x * blockDim.x + threadIdx.x;
    if (t >= 64 * K) return;
    int c = t / K, k = t % K;
    wtA[k * 64 + c] = Wl[t];
    wtB[k * 64 + c] = Wr[t];
}

// hW1[32][64] -> wt1[64][32]
__global__ void transpose_head(const float* __restrict__ hW1,
                               float* __restrict__ wt1) {
    int t = blockIdx.x * blockDim.x + threadIdx.x;
    if (t >= 32 * 64) return;
    int c = t / 64, k = t % 64;
    wt1[k * 32 + c] = hW1[t];
}

// ---------------- dual GEMM: outA = h@Wl^T, outB = h@Wr^T ----------------
// ZERO cross-lane ops. 8 nodes per wave; h elements read as wave-uniform
// scalar loads; Wt[k][lane] coalesced and L1/L2-hot. lane = output channel.

template <int K>
__global__ __launch_bounds__(256) void dual_gemm_b(
    const float* __restrict__ h, const float* __restrict__ wtA,
    const float* __restrict__ wtB, float* __restrict__ outA,
    float* __restrict__ outB, int n_nodes) {
    int tid = threadIdx.x;
    int lane = tid & 63;
    int w = tid >> 6;
    int n0 = (blockIdx.x * 4 + w) * 8;

    const float* hrow[8];
#pragma unroll
    for (int i = 0; i < 8; ++i) {
        int n = n0 + i;
        int nc = n < n_nodes ? n : n_nodes - 1;
        hrow[i] = h + (size_t)nc * K;
    }
    float accA[8], accB[8];
#pragma unroll
    for (int i = 0; i < 8; ++i) { accA[i] = 0.f; accB[i] = 0.f; }

    for (int k = 0; k < K; ++k) {
        float wa = wtA[k * 64 + lane];
        float wb = wtB[k * 64 + lane];
#pragma unroll
        for (int i = 0; i < 8; ++i) {
            float hv = hrow[i][k];  // wave-uniform scalar load
            accA[i] += hv * wa;
            accB[i] += hv * wb;
        }
    }
#pragma unroll
    for (int i = 0; i < 8; ++i) {
        int n = n0 + i;
        if (n < n_nodes) {
            outA[(size_t)n * 64 + lane] = accA[i];
            outB[(size_t)n * 64 + lane] = accB[i];
        }
    }
}

// ---------------- aggregate: mean + bias + self + BN + ReLU ----------------
// One wave per node, lane = channel. Per neighbor: one wave-uniform index
// read + one coalesced 256B gather. No cross-lane ops.

__global__ __launch_bounds__(256) void aggregate_b(
    const float* __restrict__ aggIn, const float* __restrict__ selfIn,
    const int* __restrict__ col, const int* __restrict__ cnt,
    const float* __restrict__ bl, const float* __restrict__ bn_g,
    const float* __restrict__ bn_b, const float* __restrict__ bn_m,
    const float* __restrict__ bn_v, float* __restrict__ out, int n_nodes,
    int layer) {
    int tid = threadIdx.x;
    int lane = tid & 63;
    int node = blockIdx.x * 4 + (tid >> 6);
    if (node >= n_nodes) return;
    int deg = cnt[node];
    int d = deg < PAD ? deg : PAD;
    const int* crow = col + (size_t)node * PAD;
    float acc = 0.f;
    int j = 0;
    for (; j + 3 < d; j += 4) {
        int s0 = crow[j], s1 = crow[j + 1], s2 = crow[j + 2], s3 = crow[j + 3];
        float a0 = aggIn[(size_t)s0 * 64 + lane];
        float a1 = aggIn[(size_t)s1 * 64 + lane];
        float a2 = aggIn[(size_t)s2 * 64 + lane];
        float a3 = aggIn[(size_t)s3 * 64 + lane];
        acc += (a0 + a1) + (a2 + a3);
    }
    for (; j < d; ++j)
        acc += aggIn[(size_t)crow[j] * 64 + lane];

    float t = acc / fmaxf((float)deg, 1.f) + bl[lane] +
              selfIn[(size_t)node * 64 + lane];
    int p = layer * 64 + lane;
    t = (t - bn_m[p]) * rsqrtf(bn_v[p] + 1e-5f) * bn_g[p] + bn_b[p];
    out[(size_t)node * 64 + lane] = fmaxf(t, 0.f);
}

// ---------------- head: relu(h@hW1^T + hb1) @ hW2^T + hb2 ----------------
// No shfl: lanes 0..31 compute hidden channels with uniform h loads;
// 32-wide reduce via LDS + sequential lane-0 sum. N % 4 == 0 so every
// block is full; all threads reach the barrier.

__global__ __launch_bounds__(256) void head_b(
    const float* __restrict__ h, const float* __restrict__ wt1,
    const float* __restrict__ hb1, const float* __restrict__ hW2,
    const float* __restrict__ hb2, float* __restrict__ out, int n_nodes) {
    __shared__ float red[4][32];
    int tid = threadIdx.x;
    int lane = tid & 63;
    int w = tid >> 6;
    int node = blockIdx.x * 4 + w;
    bool valid = node < n_nodes;
    int nc = valid ? node : 0;
    const float* hrow = h + (size_t)nc * 64;

    if (lane < 32) {
        float acc = 0.f;
        for (int k = 0; k < 64; ++k)
            acc += hrow[k] * wt1[k * 32 + lane];  // hrow[k] wave-uniform
        float v = fmaxf(acc + hb1[lane], 0.f);
        red[w][lane] = v * hW2[lane];
    }
    __syncthreads();
    if (valid && lane == 0) {
        float s = 0.f;
        for (int j = 0; j < 32; ++j) s += red[w][j];
        out[node] = s + hb2[0];
    }
}

// ---------------- launch ----------------

extern "C" void kernel_launch(void* const* d_in, const int* in_sizes, int n_in,
                              void* d_out, int out_size, void* d_ws,
                              size_t ws_size, hipStream_t stream) {
    const float* x = (const float*)d_in[0];
    const int* ei = (const int*)d_in[1];
    const float* Wl0 = (const float*)d_in[2];
    const float* Wr0 = (const float*)d_in[3];
    const float* bl0 = (const float*)d_in[4];
    const float* Wl1 = (const float*)d_in[5];
    const float* Wr1 = (const float*)d_in[6];
    const float* bl1 = (const float*)d_in[7];
    const float* Wl2 = (const float*)d_in[8];
    const float* Wr2 = (const float*)d_in[9];
    const float* bl2 = (const float*)d_in[10];
    const float* bn_g = (const float*)d_in[11];
    const float* bn_b = (const float*)d_in[12];
    const float* bn_m = (const float*)d_in[13];
    const float* bn_v = (const float*)d_in[14];
    const float* hW1 = (const float*)d_in[15];
    const float* hb1 = (const float*)d_in[16];
    const float* hW2 = (const float*)d_in[17];
    const float* hb2 = (const float*)d_in[18];
    float* out = (float*)d_out;

    int N = in_sizes[0] / 128;  // 100000
    int E = in_sizes[1] / 2;    // 3200000

    // workspace layout (256B-aligned slices)
    char* ws = (char*)d_ws;
    size_t col_off = ((size_t)N * 4 + 255) & ~(size_t)255;
    size_t bufA_off = col_off + (((size_t)N * PAD * 4 + 255) & ~(size_t)255);
    int* cnt = (int*)ws;
    int* col = (int*)(ws + col_off);
    float* bufA = (float*)(ws + bufA_off);  // [N,64]
    float* bufB = bufA + (size_t)N * 64;    // [N,64]
    float* bufC = bufB + (size_t)N * 64;    // [N,64]
    float* wtA0 = bufC + (size_t)N * 64;    // [128,64]
    float* wtB0 = wtA0 + 128 * 64;
    float* wtA1 = wtB0 + 128 * 64;          // [64,64]
    float* wtB1 = wtA1 + 64 * 64;
    float* wtA2 = wtB1 + 64 * 64;
    float* wtB2 = wtA2 + 64 * 64;
    float* wt1h = wtB2 + 64 * 64;           // [64,32]

    fill_zero_i32<<<(N + 255) / 256, 256, 0, stream>>>(cnt, N);
    build_adj<<<(E + 255) / 256, 256, 0, stream>>>(ei, cnt, col, E);

    transpose_pair<128><<<32, 256, 0, stream>>>(Wl0, Wr0, wtA0, wtB0);
    transpose_pair<64><<<16, 256, 0, stream>>>(Wl1, Wr1, wtA1, wtB1);
    transpose_pair<64><<<16, 256, 0, stream>>>(Wl2, Wr2, wtA2, wtB2);
    transpose_head<<<8, 256, 0, stream>>>(hW1, wt1h);

    int gemm_grid = (N + 31) / 32;  // 4 waves/block, 8 nodes/wave
    int node_grid = (N + 3) / 4;

    // layer 0 (K=128)
    dual_gemm_b<128><<<gemm_grid, 256, 0, stream>>>(x, wtA0, wtB0, bufA, bufB, N);
    aggregate_b<<<node_grid, 256, 0, stream>>>(bufA, bufB, col, cnt, bl0, bn_g,
                                               bn_b, bn_m, bn_v, bufC, N, 0);
    // layer 1 (K=64)
    dual_gemm_b<64><<<gemm_grid, 256, 0, stream>>>(bufC, wtA1, wtB1, bufA, bufB, N);
    aggregate_b<<<node_grid, 256, 0, stream>>>(bufA, bufB, col, cnt, bl1, bn_g,
                                               bn_b, bn_m, bn_v, bufC, N, 1);
    // layer 2 (K=64)
    dual_gemm_b<64><<<gemm_grid, 256, 0, stream>>>(bufC, wtA2, wtB2, bufA, bufB, N);
    aggregate_b<<<node_grid, 256, 0, stream>>>(bufA, bufB, col, cnt, bl2, bn_g,
                                               bn_b, bn_m, bn_v, bufC, N, 2);
    // head
    head_b<<<node_grid, 256, 0, stream>>>(bufC, wt1h, hb1, hW2, hb2, out, N);
}